// Round 11
// baseline (401.453 us; speedup 1.0000x reference)
//
#include <hip/hip_runtime.h>
#include <hip/hip_fp16.h>

#if defined(__has_builtin)
#if __has_builtin(__builtin_amdgcn_fdot2)
#define HAVE_FDOT2 1
#endif
#endif

typedef _Float16 hv2 __attribute__((ext_vector_type(2)));

// fp32 += dot(half2, half2) — v_dot2_f32_f16 if available.
__device__ __forceinline__ float dot2f(__half2 a, __half2 b, float c) {
#ifdef HAVE_FDOT2
    hv2 av = __builtin_bit_cast(hv2, a);
    hv2 bv = __builtin_bit_cast(hv2, b);
    return __builtin_amdgcn_fdot2(av, bv, c, false);
#else
    float2 fa = __half22float2(a), fb = __half22float2(b);
    return fmaf(fa.y, fb.y, fmaf(fa.x, fb.x, c));
#endif
}

// ---------------- Diagnostic marker: neither input mapping validated ----------------
__global__ void bad_map_marker(float* out) {
    if (threadIdx.x == 0 && blockIdx.x == 0) out[0] = 1.0e6f;
}

// ---------------- Tail (generic fallback only) ----------------
__device__ __forceinline__ void mlp_tail_compute(float* h, float* pr, int D,
        const float* g1, const float* be1,
        const float* W2, const float* b2,
        const float* g2, const float* be2,
        const float* W3, const float* b3) {
    float s = 0.f, ss = 0.f;
    #pragma unroll
    for (int d = 0; d < 64; ++d) { s += h[d]; ss += h[d] * h[d]; }
    float mu  = s * (1.f / 64.f);
    float inv = rsqrtf(ss * (1.f / 64.f) - mu * mu + 1e-5f);
    #pragma unroll
    for (int d = 0; d < 64; ++d)
        h[d] = fmaxf((h[d] - mu) * inv * g1[d] + be1[d], 0.f);

    float a2[32];
    const float4* w2v = (const float4*)W2;
    #pragma unroll
    for (int n = 0; n < 32; ++n) a2[n] = b2[n];
    for (int k = 0; k < 64; ++k) {
        float hk = h[k];
        #pragma unroll
        for (int q = 0; q < 8; ++q) {
            float4 w = w2v[k * 8 + q];
            a2[4 * q + 0] += hk * w.x;
            a2[4 * q + 1] += hk * w.y;
            a2[4 * q + 2] += hk * w.z;
            a2[4 * q + 3] += hk * w.w;
        }
    }
    s = 0.f; ss = 0.f;
    #pragma unroll
    for (int n = 0; n < 32; ++n) { s += a2[n]; ss += a2[n] * a2[n]; }
    mu  = s * (1.f / 32.f);
    inv = rsqrtf(ss * (1.f / 32.f) - mu * mu + 1e-5f);
    #pragma unroll
    for (int n = 0; n < 32; ++n)
        a2[n] = fmaxf((a2[n] - mu) * inv * g2[n] + be2[n], 0.f);

    for (int d = 0; d < D; ++d) pr[d] = b3[d];
    for (int k = 0; k < 32; ++k) {
        float hk = a2[k];
        const float* wr = W3 + k * D;
        for (int d = 0; d < D; ++d) pr[d] += hk * wr[d];
    }
}

// Coalesced diag-embed epilogue for one 256-pair tile (256-thread version).
__device__ __forceinline__ void store_diag16_tile256(const float* pp, float* out,
                                                     int P, int tile) {
    const int t = threadIdx.x;
    float4* outv = (float4*)out + (size_t)tile * 16384;
    const int pbase = tile * 256;
    #pragma unroll 8
    for (int it = 0; it < 64; ++it) {
        int g = it * 256 + t;
        int pl = g >> 6;
        int rem = g & 63;
        int d = rem >> 2;
        int c4 = rem & 3;
        float val = pp[pl * 17 + d];
        bool on = (d >> 2) == c4;
        float4 v;
        v.x = (on && (d & 3) == 0) ? val : 0.f;
        v.y = (on && (d & 3) == 1) ? val : 0.f;
        v.z = (on && (d & 3) == 2) ? val : 0.f;
        v.w = (on && (d & 3) == 3) ? val : 0.f;
        if (pbase + pl < P) outv[g] = v;
    }
}

// ---------------- Fast path stage 1 (F==128): tiled GEMM, Y[e][n] in FP16 ----------------
__global__ __launch_bounds__(256)
void precompute_y(const float* __restrict__ ef, const float* __restrict__ W1,
                  const float* __restrict__ b1, __half* __restrict__ Y, int E) {
    __shared__ __align__(16) float el[64 * 132];   // 33792 B
    const int t = threadIdx.x;
    const int ebase = blockIdx.x * 64;

    for (int idx = t; idx < 2048; idx += 256) {
        int er = idx >> 5, ec = idx & 31;
        if (ebase + er < E)
            *((float4*)(el + er * 132) + ec) =
                *((const float4*)(ef + (size_t)(ebase + er) * 128) + ec);
    }
    __syncthreads();

    const int cg = t & 15;
    const int eg = t >> 4;
    const int half_ = cg >> 3;
    const int col64 = (cg & 7) * 8;

    float acc[4][8];
    #pragma unroll
    for (int i = 0; i < 4; ++i)
        #pragma unroll
        for (int c = 0; c < 8; ++c) acc[i][c] = 0.f;

    const float* wbase = W1 + (size_t)half_ * 128 * 64 + col64;
    #pragma unroll 4
    for (int k = 0; k < 128; ++k) {
        float4 w0 = *(const float4*)(wbase + (size_t)k * 64);
        float4 w1 = *(const float4*)(wbase + (size_t)k * 64 + 4);
        float wv[8] = {w0.x, w0.y, w0.z, w0.w, w1.x, w1.y, w1.z, w1.w};
        #pragma unroll
        for (int i = 0; i < 4; ++i) {
            float a = el[(eg * 4 + i) * 132 + k];
            #pragma unroll
            for (int c = 0; c < 8; ++c) acc[i][c] += a * wv[c];
        }
    }

    float bb[8];
    #pragma unroll
    for (int c = 0; c < 8; ++c) bb[c] = (half_ == 0) ? b1[col64 + c] : 0.f;
    #pragma unroll
    for (int i = 0; i < 4; ++i) {
        int e = ebase + eg * 4 + i;
        if (e < E) {
            __half* dst = Y + (size_t)e * 128 + half_ * 64 + col64;
            __half2 hv[4];
            #pragma unroll
            for (int c = 0; c < 4; ++c)
                hv[c] = __floats2half2_rn(acc[i][2 * c] + bb[2 * c],
                                          acc[i][2 * c + 1] + bb[2 * c + 1]);
            *(float4*)dst = *(float4*)hv;   // 8 halfs = 16 B, aligned
        }
    }
}

// ---------------- Fast path stage 2: quad-cooperative gather (4 lanes/pair) ----------------
// The gather in all 1-thread/pair variants has 64 distinct cache lines per load
// instruction (zero intra-instruction coalescing) — the only untested suspect
// after byte/request/VALU/LDS/occupancy/ILP all proved null. Here 4 lanes share
// a pair: lane q loads 16B at offset q*16 of each 64B-line-aligned half-row, so
// each instruction touches 16 distinct lines (4x fewer line-requests).
// Unlike failed R5: weights stay in R9's packed LDS form (staged once per
// 256-pair tile, coalesced), GEMV1 k-split + 2x shfl_xor quad reduce, LN2
// redundant (no comm), GEMV2 output-split (no reduce). Natural ~90 VGPR, no
// min-waves cap (R6/R8 spill trap).
// Lane q covers k in [8q,8q+8) u [32+8q, 32+8q+8)  (k2 in [4q,4q+4) u [16+4q,16+4q+4)).
__global__ __launch_bounds__(1024)
void sheaf_pairs_quad(const int* __restrict__ pi, const int* __restrict__ pj,
                      const __half* __restrict__ Y,
                      const float* __restrict__ g1, const float* __restrict__ be1,
                      const float* __restrict__ W2, const float* __restrict__ b2,
                      const float* __restrict__ g2, const float* __restrict__ be2,
                      const float* __restrict__ W3, const float* __restrict__ b3,
                      float* __restrict__ out, int P) {
    __shared__ float pp[256 * 20];                    // 20480 B, float4-aligned rows
    __shared__ __align__(16) __half2 w2p[32 * 36];    // [k2][n], row padded 32->36 (bank spread)
    __shared__ __align__(16) __half2 w3p[16 * 16];    // [k2][n]
    __shared__ float g1s[64], be1s[64], b2s[32], g2s[32], be2s[32], b3s[16];

    const int t  = threadIdx.x;
    const int pl = t >> 2;          // pair within tile (0..255)
    const int q  = t & 3;           // quad lane
    const int pbase = blockIdx.x * 256;
    int p  = pbase + pl;
    int pc = p < P ? p : P - 1;
    int i = pi[pc], j = pj[pc];

    // Quad-cooperative gather: 4 x 16B per lane; quad spans each 64B chunk contiguously.
    const char* rowi = (const char*)(Y + (size_t)i * 128);   // 256 B row
    const char* rowj = (const char*)(Y + (size_t)j * 128);
    float4 a0 = *(const float4*)(rowi + q * 16);             // Ya k=8q..8q+8
    float4 a1 = *(const float4*)(rowi + 64 + q * 16);        // Ya k=32+8q..
    float4 b0 = *(const float4*)(rowj + 128 + q * 16);       // Yb k=8q..
    float4 b1 = *(const float4*)(rowj + 192 + q * 16);       // Yb k=32+8q..

    // Stage packed weights into LDS (1024 threads, coalesced; overlaps gather latency).
    {
        int k2 = t >> 5, n = t & 31;
        w2p[k2 * 36 + n] = __floats2half2_rn(W2[(2 * k2) * 32 + n],
                                             W2[(2 * k2 + 1) * 32 + n]);
        if (t < 256) {
            int k2b = t >> 4, nb = t & 15;
            w3p[k2b * 16 + nb] = __floats2half2_rn(W3[(2 * k2b) * 16 + nb],
                                                   W3[(2 * k2b + 1) * 16 + nb]);
        }
        if (t < 64)                 { g1s[t] = g1[t]; be1s[t] = be1[t]; }
        else if (t < 96)            b2s[t - 64]   = b2[t - 64];
        else if (t < 128)           g2s[t - 96]   = g2[t - 96];
        else if (t < 160)           be2s[t - 128] = be2[t - 128];
        else if (t < 176)           b3s[t - 160]  = b3[t - 160];
    }

    // h (16 local features) in fp32.
    float h[16];
    {
        const __half2* pa = (const __half2*)&a0;
        const __half2* pb = (const __half2*)&b0;
        #pragma unroll
        for (int u = 0; u < 4; ++u) {
            float2 fa = __half22float2(pa[u]);
            float2 fb = __half22float2(pb[u]);
            h[2 * u + 0] = fa.x + fb.x;
            h[2 * u + 1] = fa.y + fb.y;
        }
        const __half2* pa1 = (const __half2*)&a1;
        const __half2* pb1 = (const __half2*)&b1;
        #pragma unroll
        for (int u = 0; u < 4; ++u) {
            float2 fa = __half22float2(pa1[u]);
            float2 fb = __half22float2(pb1[u]);
            h[8 + 2 * u + 0] = fa.x + fb.x;
            h[8 + 2 * u + 1] = fa.y + fb.y;
        }
    }

    // LN1 stats: local 16 + quad butterfly.
    float s = 0.f, ss = 0.f;
    #pragma unroll
    for (int m = 0; m < 16; ++m) { s += h[m]; ss += h[m] * h[m]; }
    s  += __shfl_xor(s, 1);  ss += __shfl_xor(ss, 1);
    s  += __shfl_xor(s, 2);  ss += __shfl_xor(ss, 2);
    float mu  = s * (1.f / 64.f);
    float inv = rsqrtf(ss * (1.f / 64.f) - mu * mu + 1e-5f);

    __syncthreads();   // weights staged

    // Normalize + ReLU -> packed hp[8] (half2). k-map: m<8 -> k=8q+m; else k=32+8q+(m-8).
    __half2 hp[8];
    #pragma unroll
    for (int m2 = 0; m2 < 4; ++m2) {
        int k = 8 * q + 2 * m2;
        float h0 = fmaxf((h[2 * m2]     - mu) * inv * g1s[k]     + be1s[k],     0.f);
        float h1 = fmaxf((h[2 * m2 + 1] - mu) * inv * g1s[k + 1] + be1s[k + 1], 0.f);
        hp[m2] = __floats2half2_rn(h0, h1);
    }
    #pragma unroll
    for (int m2 = 0; m2 < 4; ++m2) {
        int k = 32 + 8 * q + 2 * m2;
        float h0 = fmaxf((h[8 + 2 * m2]     - mu) * inv * g1s[k]     + be1s[k],     0.f);
        float h1 = fmaxf((h[8 + 2 * m2 + 1] - mu) * inv * g1s[k + 1] + be1s[k + 1], 0.f);
        hp[4 + m2] = __floats2half2_rn(h0, h1);
    }

    // GEMV1 k-split partials: lane's 8 k2-rows of w2p.
    float a2[32];
    #pragma unroll
    for (int n = 0; n < 32; ++n) a2[n] = 0.f;
    #pragma unroll
    for (int d = 0; d < 4; ++d) {
        #pragma unroll
        for (int g = 0; g < 2; ++g) {
            int k2 = (g == 0) ? (4 * q + d) : (16 + 4 * q + d);
            __half2 hk = hp[4 * g + d];
            const float4* wrow = (const float4*)(w2p + k2 * 36);
            #pragma unroll
            for (int u = 0; u < 8; ++u) {
                float4 wq = wrow[u];
                const __half2* wp = (const __half2*)&wq;
                a2[4 * u + 0] = dot2f(hk, wp[0], a2[4 * u + 0]);
                a2[4 * u + 1] = dot2f(hk, wp[1], a2[4 * u + 1]);
                a2[4 * u + 2] = dot2f(hk, wp[2], a2[4 * u + 2]);
                a2[4 * u + 3] = dot2f(hk, wp[3], a2[4 * u + 3]);
            }
        }
    }
    // Quad reduce -> every lane holds full a2.
    #pragma unroll
    for (int n = 0; n < 32; ++n) {
        a2[n] += __shfl_xor(a2[n], 1);
        a2[n] += __shfl_xor(a2[n], 2);
    }

    // + b2, LN2 + ReLU (redundant across quad, no comm).
    s = 0.f; ss = 0.f;
    #pragma unroll
    for (int n = 0; n < 32; ++n) {
        a2[n] += b2s[n];
        s += a2[n]; ss += a2[n] * a2[n];
    }
    mu  = s * (1.f / 32.f);
    inv = rsqrtf(ss * (1.f / 32.f) - mu * mu + 1e-5f);
    #pragma unroll
    for (int n = 0; n < 32; ++n)
        a2[n] = fmaxf((a2[n] - mu) * inv * g2s[n] + be2s[n], 0.f);

    // GEMV2 output-split: lane q computes pr[n], n in [4q, 4q+4). No reduce.
    __half2 ap[16];
    #pragma unroll
    for (int k2 = 0; k2 < 16; ++k2)
        ap[k2] = __floats2half2_rn(a2[2 * k2], a2[2 * k2 + 1]);

    float pr0 = b3s[4 * q + 0], pr1 = b3s[4 * q + 1];
    float pr2 = b3s[4 * q + 2], pr3 = b3s[4 * q + 3];
    #pragma unroll 4
    for (int k2 = 0; k2 < 16; ++k2) {
        float4 wq = *(const float4*)(w3p + k2 * 16 + 4 * q);
        const __half2* wp = (const __half2*)&wq;
        __half2 ak = ap[k2];
        pr0 = dot2f(ak, wp[0], pr0);
        pr1 = dot2f(ak, wp[1], pr1);
        pr2 = dot2f(ak, wp[2], pr2);
        pr3 = dot2f(ak, wp[3], pr3);
    }
    *(float4*)(pp + pl * 20 + 4 * q) = make_float4(pr0, pr1, pr2, pr3);
    __syncthreads();

    // Diag-embed store: 16384 float4 chunks / 1024 threads = 16 per thread.
    float4* outv = (float4*)out + (size_t)blockIdx.x * 16384;
    #pragma unroll 4
    for (int it = 0; it < 16; ++it) {
        int g = it * 1024 + t;
        int pl2 = g >> 6;
        int rem = g & 63;
        int d = rem >> 2;
        int c4 = rem & 3;
        float val = pp[pl2 * 20 + d];
        bool on = (d >> 2) == c4;
        float4 v;
        v.x = (on && (d & 3) == 0) ? val : 0.f;
        v.y = (on && (d & 3) == 1) ? val : 0.f;
        v.z = (on && (d & 3) == 2) ? val : 0.f;
        v.w = (on && (d & 3) == 3) ? val : 0.f;
        if (pbase + pl2 < P) outv[g] = v;
    }
}

// ---------------- Generic fallback: runtime F, D (<=32), all fp32 ----------------
__global__ __launch_bounds__(256)
void sheaf_generic(const float* __restrict__ ef,
                   const int* __restrict__ pi, const int* __restrict__ pj,
                   const float* __restrict__ W1, const float* __restrict__ b1,
                   const float* __restrict__ g1, const float* __restrict__ be1,
                   const float* __restrict__ W2, const float* __restrict__ b2,
                   const float* __restrict__ g2, const float* __restrict__ be2,
                   const float* __restrict__ W3, const float* __restrict__ b3,
                   float* __restrict__ out, int P, int F, int D) {
    __shared__ float pp[256 * 17];
    int p = blockIdx.x * 256 + threadIdx.x;
    int pc = p < P ? p : P - 1;
    int i = pi[pc], j = pj[pc];
    const float* efi = ef + (size_t)i * F;
    const float* efj = ef + (size_t)j * F;
    float h[64];
    #pragma unroll
    for (int n = 0; n < 64; ++n) h[n] = b1[n];
    for (int k = 0; k < F; ++k) {
        float ei = efi[k];
        float ej = efj[k];
        const float* wi = W1 + (size_t)k * 64;
        const float* wj = W1 + (size_t)(F + k) * 64;
        #pragma unroll
        for (int n = 0; n < 64; ++n) h[n] += ei * wi[n] + ej * wj[n];
    }
    float pr[32];
    mlp_tail_compute(h, pr, D, g1, be1, W2, b2, g2, be2, W3, b3);

    if (D == 16) {
        #pragma unroll
        for (int d = 0; d < 16; ++d) pp[threadIdx.x * 17 + d] = pr[d];
        __syncthreads();
        store_diag16_tile256(pp, out, P, blockIdx.x);
    } else {
        if (p < P) {
            float* po = out + (size_t)p * D * D;
            for (int r = 0; r < D; ++r) {
                float dv = pr[r];
                for (int c = 0; c < D; ++c) po[r * D + c] = (r == c) ? dv : 0.f;
            }
        }
    }
}

// ---------------- Host side: derive ALL dims from in_sizes/out_size ----------------
struct Map { int ef, pi, pj, w1, b1, g1, be1, w2, b2, g2, be2, w3, b3; };

static bool validate_map(const Map& m, const int* s, int n_in, long out_size,
                         int* Fo, int* Eo, int* Do, int* Po) {
    if (n_in < 13) return false;
    if (s[m.b1] != 64 || s[m.g1] != 64 || s[m.be1] != 64) return false;
    if (s[m.b2] != 32 || s[m.g2] != 32 || s[m.be2] != 32) return false;
    if (s[m.w2] != 64 * 32) return false;
    long w1 = s[m.w1];
    if (w1 <= 0 || (w1 % 128) != 0) return false;       // W1 = (2F, 64)
    long F = w1 / 128;
    if (F <= 0) return false;
    int D = s[m.b3];
    if (D <= 0 || D > 32) return false;
    if (s[m.w3] != 32 * D) return false;
    long P = s[m.pi];
    if (P <= 0 || s[m.pj] != P) return false;
    long ef = s[m.ef];
    if (ef <= 0 || (ef % F) != 0) return false;
    long E = ef / F;
    if (out_size != P * D * D) return false;
    *Fo = (int)F; *Eo = (int)E; *Do = D; *Po = (int)P;
    return true;
}

extern "C" void kernel_launch(void* const* d_in, const int* in_sizes, int n_in,
                              void* d_out, int out_size, void* d_ws, size_t ws_size,
                              hipStream_t stream) {
    const Map pos   = {0, 1, 2, 3, 4, 5, 6, 7, 8, 9, 10, 11, 12};
    const Map alpha = {8, 11, 12, 0, 3, 9, 6, 1, 4, 10, 7, 2, 5};

    int F = 0, E = 0, D = 0, P = 0;
    Map m;
    if (validate_map(pos, in_sizes, n_in, (long)out_size, &F, &E, &D, &P)) {
        m = pos;
    } else if (validate_map(alpha, in_sizes, n_in, (long)out_size, &F, &E, &D, &P)) {
        m = alpha;
    } else {
        bad_map_marker<<<dim3(1), dim3(64), 0, stream>>>((float*)d_out);
        return;
    }

    const float* ef  = (const float*)d_in[m.ef];
    const int*   pi  = (const int*)d_in[m.pi];
    const int*   pj  = (const int*)d_in[m.pj];
    const float* W1  = (const float*)d_in[m.w1];
    const float* b1  = (const float*)d_in[m.b1];
    const float* g1  = (const float*)d_in[m.g1];
    const float* be1 = (const float*)d_in[m.be1];
    const float* W2  = (const float*)d_in[m.w2];
    const float* b2  = (const float*)d_in[m.b2];
    const float* g2  = (const float*)d_in[m.g2];
    const float* be2 = (const float*)d_in[m.be2];
    const float* W3  = (const float*)d_in[m.w3];
    const float* b3  = (const float*)d_in[m.b3];
    float* out = (float*)d_out;

    const size_t y_bytes = (size_t)E * 128 * sizeof(__half);

    if (F == 128 && D == 16 && ws_size >= y_bytes) {
        __half* Y = (__half*)d_ws;
        precompute_y<<<dim3((E + 63) / 64), dim3(256), 0, stream>>>(ef, W1, b1, Y, E);
        int ntiles = (P + 255) / 256;
        sheaf_pairs_quad<<<dim3(ntiles), dim3(1024), 0, stream>>>(
            pi, pj, Y, g1, be1, W2, b2, g2, be2, W3, b3, out, P);
    } else {
        sheaf_generic<<<dim3((P + 255) / 256), dim3(256), 0, stream>>>(
            ef, pi, pj, W1, b1, g1, be1, W2, b2, g2, be2, W3, b3, out, P, F, D);
    }
}

// Round 12
// 378.874 us; speedup vs baseline: 1.0596x; 1.0596x over previous
//
#include <hip/hip_runtime.h>
#include <hip/hip_fp16.h>

// Native vector type — __builtin_nontemporal_store rejects HIP's float4 class.
typedef float f32x4 __attribute__((ext_vector_type(4)));

// ---------------- Diagnostic marker: neither input mapping validated ----------------
__global__ void bad_map_marker(float* out) {
    if (threadIdx.x == 0 && blockIdx.x == 0) out[0] = 1.0e6f;
}

// ---------------- Tail: LN1(64)+ReLU -> L2(64,32) -> LN2+ReLU -> L3(32,D) ----------------
__device__ __forceinline__ void mlp_tail_compute(float* h, float* pr, int D,
        const float* g1, const float* be1,
        const float* W2, const float* b2,
        const float* g2, const float* be2,
        const float* W3, const float* b3) {
    float s = 0.f, ss = 0.f;
    #pragma unroll
    for (int d = 0; d < 64; ++d) { s += h[d]; ss += h[d] * h[d]; }
    float mu  = s * (1.f / 64.f);
    float inv = rsqrtf(ss * (1.f / 64.f) - mu * mu + 1e-5f);
    #pragma unroll
    for (int d = 0; d < 64; ++d)
        h[d] = fmaxf((h[d] - mu) * inv * g1[d] + be1[d], 0.f);

    float a2[32];
    const float4* w2v = (const float4*)W2;
    #pragma unroll
    for (int n = 0; n < 32; ++n) a2[n] = b2[n];
    for (int k = 0; k < 64; ++k) {
        float hk = h[k];
        #pragma unroll
        for (int q = 0; q < 8; ++q) {
            float4 w = w2v[k * 8 + q];
            a2[4 * q + 0] += hk * w.x;
            a2[4 * q + 1] += hk * w.y;
            a2[4 * q + 2] += hk * w.z;
            a2[4 * q + 3] += hk * w.w;
        }
    }
    s = 0.f; ss = 0.f;
    #pragma unroll
    for (int n = 0; n < 32; ++n) { s += a2[n]; ss += a2[n] * a2[n]; }
    mu  = s * (1.f / 32.f);
    inv = rsqrtf(ss * (1.f / 32.f) - mu * mu + 1e-5f);
    #pragma unroll
    for (int n = 0; n < 32; ++n)
        a2[n] = fmaxf((a2[n] - mu) * inv * g2[n] + be2[n], 0.f);

    for (int d = 0; d < D; ++d) pr[d] = b3[d];
    for (int k = 0; k < 32; ++k) {
        float hk = a2[k];
        const float* wr = W3 + k * D;
        for (int d = 0; d < D; ++d) pr[d] += hk * wr[d];
    }
}

// Coalesced diag-embed epilogue, 256 pairs/block. NONTEMPORAL stores: the output
// is write-once; keeping it OUT of L2 is what lets the 5 MB Ya/Yb gather tables
// stay L2-resident (fp16 Y alone was only -7us because regular stores evicted it).
__device__ __forceinline__ void store_diag16_f32_256(const float* pp, float* out, int P) {
    const int t = threadIdx.x;
    f32x4* outv = (f32x4*)out + (size_t)blockIdx.x * 16384;
    const int pbase = blockIdx.x * 256;
    #pragma unroll 8
    for (int it = 0; it < 64; ++it) {
        int g = it * 256 + t;
        int pl = g >> 6;
        int rem = g & 63;
        int d = rem >> 2;
        int c4 = rem & 3;
        float val = pp[pl * 17 + d];
        bool on = (d >> 2) == c4;
        f32x4 v;
        v.x = (on && (d & 3) == 0) ? val : 0.f;
        v.y = (on && (d & 3) == 1) ? val : 0.f;
        v.z = (on && (d & 3) == 2) ? val : 0.f;
        v.w = (on && (d & 3) == 3) ? val : 0.f;
        if (pbase + pl < P) __builtin_nontemporal_store(v, &outv[g]);
    }
}

// ---------------- Fast path stage 1 (F==128): tiled GEMM -> SPLIT fp16 Ya/Yb ----------------
// Ya[e][0..63] = first-half cols (used by i-gathers), Yb[e][0..63] = second-half
// cols (used by j-gathers). 2.5 MB each: each gather stream fits per-XCD L2.
__global__ __launch_bounds__(256)
void precompute_y(const float* __restrict__ ef, const float* __restrict__ W1,
                  const float* __restrict__ b1, __half* __restrict__ Ya,
                  __half* __restrict__ Yb, int E) {
    __shared__ __align__(16) float el[64 * 132];   // 33792 B
    const int t = threadIdx.x;
    const int ebase = blockIdx.x * 64;

    for (int idx = t; idx < 2048; idx += 256) {
        int er = idx >> 5, ec = idx & 31;
        if (ebase + er < E)
            *((float4*)(el + er * 132) + ec) =
                *((const float4*)(ef + (size_t)(ebase + er) * 128) + ec);
    }
    __syncthreads();

    const int cg = t & 15;
    const int eg = t >> 4;
    const int half_ = cg >> 3;      // 0 -> Ya (cols 0..63), 1 -> Yb (cols 64..127)
    const int col64 = (cg & 7) * 8;

    float acc[4][8];
    #pragma unroll
    for (int i = 0; i < 4; ++i)
        #pragma unroll
        for (int c = 0; c < 8; ++c) acc[i][c] = 0.f;

    const float* wbase = W1 + (size_t)half_ * 128 * 64 + col64;
    #pragma unroll 4
    for (int k = 0; k < 128; ++k) {
        float4 w0 = *(const float4*)(wbase + (size_t)k * 64);
        float4 w1 = *(const float4*)(wbase + (size_t)k * 64 + 4);
        float wv[8] = {w0.x, w0.y, w0.z, w0.w, w1.x, w1.y, w1.z, w1.w};
        #pragma unroll
        for (int i = 0; i < 4; ++i) {
            float a = el[(eg * 4 + i) * 132 + k];
            #pragma unroll
            for (int c = 0; c < 8; ++c) acc[i][c] += a * wv[c];
        }
    }

    float bb[8];
    #pragma unroll
    for (int c = 0; c < 8; ++c) bb[c] = (half_ == 0) ? b1[col64 + c] : 0.f;
    __half* base = (half_ == 0) ? Ya : Yb;
    #pragma unroll
    for (int i = 0; i < 4; ++i) {
        int e = ebase + eg * 4 + i;
        if (e < E) {
            __half* dst = base + (size_t)e * 64 + col64;
            __half2 hv[4];
            #pragma unroll
            for (int c = 0; c < 4; ++c)
                hv[c] = __floats2half2_rn(acc[i][2 * c] + bb[2 * c],
                                          acc[i][2 * c + 1] + bb[2 * c + 1]);
            *(float4*)dst = *(float4*)hv;   // 8 halfs = 16 B, aligned
        }
    }
}

// ---------------- Fast path stage 2: 1 thread/pair, split fp16 gather, weights in LDS ----------------
// R7 structure (best measured, 382us). Changes: Ya/Yb split arrays + nt output
// stores (see store_diag16_f32_256). NO min-waves launch_bounds (R6/R8 spills).
__global__ __launch_bounds__(256)
void sheaf_pairs(const int* __restrict__ pi, const int* __restrict__ pj,
                 const __half* __restrict__ Ya, const __half* __restrict__ Yb,
                 const float* __restrict__ g1, const float* __restrict__ be1,
                 const float* __restrict__ W2, const float* __restrict__ b2,
                 const float* __restrict__ g2, const float* __restrict__ be2,
                 const float* __restrict__ W3, const float* __restrict__ b3,
                 float* __restrict__ out, int P) {
    __shared__ float pp[256 * 17];
    __shared__ __align__(16) float w2s[64 * 32];
    __shared__ __align__(16) float w3s[32 * 16];
    __shared__ float g1s[64], be1s[64], b2s[32], g2s[32], be2s[32], b3s[16];

    const int t = threadIdx.x;
    int p = blockIdx.x * 256 + t;
    int pc = p < P ? p : P - 1;
    int i = pi[pc], j = pj[pc];

    // Gather: 128 B per side (8 x 16B chunks), packed fp16, from 2.5 MB tables.
    const float4* y1 = (const float4*)(Ya + (size_t)i * 64);
    const float4* y2 = (const float4*)(Yb + (size_t)j * 64);
    float4 ra[8], rb[8];
    #pragma unroll
    for (int q = 0; q < 8; ++q) { ra[q] = y1[q]; rb[q] = y2[q]; }

    // Stage all MLP-tail weights into LDS (once per block) — overlaps gather latency.
    {
        const float4* s2 = (const float4*)W2;      // 512 float4
        float4* d2 = (float4*)w2s;
        d2[t]       = s2[t];
        d2[t + 256] = s2[t + 256];
        if (t < 128) ((float4*)w3s)[t] = ((const float4*)W3)[t];   // 128 float4
        if (t < 64)                 { g1s[t] = g1[t]; be1s[t] = be1[t]; }
        else if (t < 96)            b2s[t - 64]   = b2[t - 64];
        else if (t < 128)           g2s[t - 96]   = g2[t - 96];
        else if (t < 160)           be2s[t - 128] = be2[t - 128];
        else if (t < 176)           b3s[t - 160]  = b3[t - 160];
    }

    float h[64];
    #pragma unroll
    for (int q = 0; q < 8; ++q) {
        const __half2* ha = (const __half2*)&ra[q];
        const __half2* hb = (const __half2*)&rb[q];
        #pragma unroll
        for (int u = 0; u < 4; ++u) {
            float2 fa = __half22float2(ha[u]);
            float2 fb = __half22float2(hb[u]);
            h[8 * q + 2 * u + 0] = fa.x + fb.x;
            h[8 * q + 2 * u + 1] = fa.y + fb.y;
        }
    }
    __syncthreads();

    float pr[16];
    mlp_tail_compute(h, pr, 16, g1s, be1s, w2s, b2s, g2s, be2s, w3s, b3s);
    #pragma unroll
    for (int d = 0; d < 16; ++d) pp[t * 17 + d] = pr[d];
    __syncthreads();
    store_diag16_f32_256(pp, out, P);
}

// ---------------- Generic fallback: runtime F, D (<=32), all fp32 ----------------
__global__ __launch_bounds__(256)
void sheaf_generic(const float* __restrict__ ef,
                   const int* __restrict__ pi, const int* __restrict__ pj,
                   const float* __restrict__ W1, const float* __restrict__ b1,
                   const float* __restrict__ g1, const float* __restrict__ be1,
                   const float* __restrict__ W2, const float* __restrict__ b2,
                   const float* __restrict__ g2, const float* __restrict__ be2,
                   const float* __restrict__ W3, const float* __restrict__ b3,
                   float* __restrict__ out, int P, int F, int D) {
    __shared__ float pp[256 * 17];
    int p = blockIdx.x * 256 + threadIdx.x;
    int pc = p < P ? p : P - 1;
    int i = pi[pc], j = pj[pc];
    const float* efi = ef + (size_t)i * F;
    const float* efj = ef + (size_t)j * F;
    float h[64];
    #pragma unroll
    for (int n = 0; n < 64; ++n) h[n] = b1[n];
    for (int k = 0; k < F; ++k) {
        float ei = efi[k];
        float ej = efj[k];
        const float* wi = W1 + (size_t)k * 64;
        const float* wj = W1 + (size_t)(F + k) * 64;
        #pragma unroll
        for (int n = 0; n < 64; ++n) h[n] += ei * wi[n] + ej * wj[n];
    }
    float pr[32];
    mlp_tail_compute(h, pr, D, g1, be1, W2, b2, g2, be2, W3, b3);

    if (D == 16) {
        #pragma unroll
        for (int d = 0; d < 16; ++d) pp[threadIdx.x * 17 + d] = pr[d];
        __syncthreads();
        store_diag16_f32_256(pp, out, P);
    } else {
        if (p < P) {
            float* po = out + (size_t)p * D * D;
            for (int r = 0; r < D; ++r) {
                float dv = pr[r];
                for (int c = 0; c < D; ++c) po[r * D + c] = (r == c) ? dv : 0.f;
            }
        }
    }
}

// ---------------- Host side: derive ALL dims from in_sizes/out_size ----------------
struct Map { int ef, pi, pj, w1, b1, g1, be1, w2, b2, g2, be2, w3, b3; };

static bool validate_map(const Map& m, const int* s, int n_in, long out_size,
                         int* Fo, int* Eo, int* Do, int* Po) {
    if (n_in < 13) return false;
    if (s[m.b1] != 64 || s[m.g1] != 64 || s[m.be1] != 64) return false;
    if (s[m.b2] != 32 || s[m.g2] != 32 || s[m.be2] != 32) return false;
    if (s[m.w2] != 64 * 32) return false;
    long w1 = s[m.w1];
    if (w1 <= 0 || (w1 % 128) != 0) return false;       // W1 = (2F, 64)
    long F = w1 / 128;
    if (F <= 0) return false;
    int D = s[m.b3];
    if (D <= 0 || D > 32) return false;
    if (s[m.w3] != 32 * D) return false;
    long P = s[m.pi];
    if (P <= 0 || s[m.pj] != P) return false;
    long ef = s[m.ef];
    if (ef <= 0 || (ef % F) != 0) return false;
    long E = ef / F;
    if (out_size != P * D * D) return false;
    *Fo = (int)F; *Eo = (int)E; *Do = D; *Po = (int)P;
    return true;
}

extern "C" void kernel_launch(void* const* d_in, const int* in_sizes, int n_in,
                              void* d_out, int out_size, void* d_ws, size_t ws_size,
                              hipStream_t stream) {
    const Map pos   = {0, 1, 2, 3, 4, 5, 6, 7, 8, 9, 10, 11, 12};
    const Map alpha = {8, 11, 12, 0, 3, 9, 6, 1, 4, 10, 7, 2, 5};

    int F = 0, E = 0, D = 0, P = 0;
    Map m;
    if (validate_map(pos, in_sizes, n_in, (long)out_size, &F, &E, &D, &P)) {
        m = pos;
    } else if (validate_map(alpha, in_sizes, n_in, (long)out_size, &F, &E, &D, &P)) {
        m = alpha;
    } else {
        bad_map_marker<<<dim3(1), dim3(64), 0, stream>>>((float*)d_out);
        return;
    }

    const float* ef  = (const float*)d_in[m.ef];
    const int*   pi  = (const int*)d_in[m.pi];
    const int*   pj  = (const int*)d_in[m.pj];
    const float* W1  = (const float*)d_in[m.w1];
    const float* b1  = (const float*)d_in[m.b1];
    const float* g1  = (const float*)d_in[m.g1];
    const float* be1 = (const float*)d_in[m.be1];
    const float* W2  = (const float*)d_in[m.w2];
    const float* b2  = (const float*)d_in[m.b2];
    const float* g2  = (const float*)d_in[m.g2];
    const float* be2 = (const float*)d_in[m.be2];
    const float* W3  = (const float*)d_in[m.w3];
    const float* b3  = (const float*)d_in[m.b3];
    float* out = (float*)d_out;

    const size_t ya_bytes = (size_t)E * 64 * sizeof(__half);
    const size_t y_bytes  = 2 * ya_bytes;

    if (F == 128 && D == 16 && ws_size >= y_bytes) {
        __half* Ya = (__half*)d_ws;
        __half* Yb = (__half*)((char*)d_ws + ya_bytes);
        precompute_y<<<dim3((E + 63) / 64), dim3(256), 0, stream>>>(ef, W1, b1, Ya, Yb, E);
        sheaf_pairs<<<dim3((P + 255) / 256), dim3(256), 0, stream>>>(
            pi, pj, Ya, Yb, g1, be1, W2, b2, g2, be2, W3, b3, out, P);
    } else {
        sheaf_generic<<<dim3((P + 255) / 256), dim3(256), 0, stream>>>(
            ef, pi, pj, W1, b1, g1, be1, W2, b2, g2, be2, W3, b3, out, P, F, D);
    }
}